// Round 8
// baseline (234.119 us; speedup 1.0000x reference)
//
#include <hip/hip_runtime.h>
#include <hip/hip_bf16.h>
#include <cstdint>

#define B_ 2
#define S_ 2048
#define D_ 1024
#define H_ 16
#define HD_ 64

#define SCALE_LOG2 0.18033688011112042f   // (1/8) * log2(e), folded into Q proj

typedef __attribute__((ext_vector_type(8))) __bf16 bf16x8;
typedef __attribute__((ext_vector_type(8))) unsigned short ushort8;
typedef __attribute__((ext_vector_type(4))) unsigned short ushort4v;
typedef __attribute__((ext_vector_type(4))) float f32x4;
typedef __attribute__((ext_vector_type(16))) float f32x16;

__device__ __forceinline__ unsigned short f2bf(float f) {
  __bf16 h = (__bf16)f;                       // native v_cvt (RNE)
  return __builtin_bit_cast(unsigned short, h);
}

__device__ __forceinline__ float bf2f(unsigned short u) {
  union { unsigned int i; float f; } v; v.i = ((unsigned int)u) << 16; return v.f;
}

__device__ __forceinline__ float fexp2(float x) {
#if __has_builtin(__builtin_amdgcn_exp2f)
  return __builtin_amdgcn_exp2f(x);           // raw v_exp_f32
#else
  return exp2f(x);
#endif
}

__device__ __forceinline__ f32x4 mfma16(bf16x8 a, bf16x8 b, f32x4 c) {
  return __builtin_amdgcn_mfma_f32_16x16x32_bf16(a, b, c, 0, 0, 0);
}
__device__ __forceinline__ f32x16 mfma32(bf16x8 a, bf16x8 b, f32x16 c) {
  return __builtin_amdgcn_mfma_f32_32x32x16_bf16(a, b, c, 0, 0, 0);
}

// LDS-hazard-only barrier: does NOT drain vmcnt, so in-flight global stores
// keep draining in the background.
#define LGKM_BARRIER()                                        \
  do {                                                        \
    asm volatile("s_waitcnt lgkmcnt(0)" ::: "memory");        \
    __builtin_amdgcn_s_barrier();                             \
  } while (0)

// ---------------------------------------------------------------------------
// Kernel A: QKV projections. C[m][n] = sum_k X[m][k] * W[n][k]  (NT GEMM)
// z=0: Q -> qh[(b*H+h)*S + s][hd]  (PRE-SCALED by (1/8)*log2(e))
// z=1: K -> kh, same layout
// z=2: V -> vt[(b*H+h)*HD + hd][s]  (transposed for PV B-operand)
// ---------------------------------------------------------------------------
__global__ __launch_bounds__(256) void proj_qkv_kernel(
    const float* __restrict__ qin, const float* __restrict__ kin,
    const float* __restrict__ vin, const float* __restrict__ wq,
    const float* __restrict__ wk, const float* __restrict__ wv,
    unsigned short* __restrict__ qh, unsigned short* __restrict__ kh,
    unsigned short* __restrict__ vt)
{
  __shared__ unsigned short As[128][40];  // pad 32->40: stride 80B spreads banks
  __shared__ unsigned short Bs[128][40];

  const int z = blockIdx.z;
  const float* X = (z == 0) ? qin : (z == 1) ? kin : vin;
  const float* W = (z == 0) ? wq : (z == 1) ? wk : wv;
  unsigned short* dst = (z == 0) ? qh : (z == 1) ? kh : vt;
  const float osc = (z == 0) ? SCALE_LOG2 : 1.0f;

  // bijective chunked XCD swizzle over the 256 (x,y) blocks
  const int lin = blockIdx.x + 8 * blockIdx.y;
  const int swz = (lin & 7) * 32 + (lin >> 3);
  const int bx = swz & 7, by = swz >> 3;

  const int tid = threadIdx.x;
  const int lane = tid & 63, wid = tid >> 6;
  const int c = lane & 15, g = lane >> 4;
  const int wr = wid >> 1, wc = wid & 1;           // 2x2 waves, 64x64 each
  const int m0 = by * 128, n0 = bx * 128;

  const int sr = tid >> 1, sh = tid & 1;
  const float* Ap = X + (size_t)(m0 + sr) * D_ + sh * 16;
  const float* Bp = W + (size_t)(n0 + sr) * D_ + sh * 16;

  float ar[16], br[16];
  f32x4 acc[4][4];
#pragma unroll
  for (int i = 0; i < 4; ++i)
#pragma unroll
    for (int j = 0; j < 4; ++j) acc[i][j] = (f32x4){0.f, 0.f, 0.f, 0.f};

  auto ldg_tile = [&](int kt) {
    const float* ap = Ap + kt * 32;
    const float* bp = Bp + kt * 32;
#pragma unroll
    for (int j = 0; j < 4; ++j) {
      *(f32x4*)(ar + 4 * j) = *(const f32x4*)(ap + 4 * j);
      *(f32x4*)(br + 4 * j) = *(const f32x4*)(bp + 4 * j);
    }
  };
  auto sts_tile = [&]() {
    unsigned short ta[16], tb[16];
#pragma unroll
    for (int j = 0; j < 16; ++j) { ta[j] = f2bf(ar[j]); tb[j] = f2bf(br[j]); }
    *(ushort8*)&As[sr][sh * 16]     = *(ushort8*)&ta[0];
    *(ushort8*)&As[sr][sh * 16 + 8] = *(ushort8*)&ta[8];
    *(ushort8*)&Bs[sr][sh * 16]     = *(ushort8*)&tb[0];
    *(ushort8*)&Bs[sr][sh * 16 + 8] = *(ushort8*)&tb[8];
  };

  ldg_tile(0);
  sts_tile();
  __syncthreads();

  for (int kt = 0; kt < 32; ++kt) {
    if (kt < 31) ldg_tile(kt + 1);
    bf16x8 af[4], bfr[4];
#pragma unroll
    for (int i = 0; i < 4; ++i) af[i]  = *(bf16x8*)&As[wr * 64 + i * 16 + c][g * 8];
#pragma unroll
    for (int i = 0; i < 4; ++i) bfr[i] = *(bf16x8*)&Bs[wc * 64 + i * 16 + c][g * 8];
#pragma unroll
    for (int mi = 0; mi < 4; ++mi)
#pragma unroll
      for (int ni = 0; ni < 4; ++ni)
        acc[mi][ni] = mfma16(af[mi], bfr[ni], acc[mi][ni]);
    __syncthreads();
    if (kt < 31) { sts_tile(); __syncthreads(); }
  }

#pragma unroll
  for (int mi = 0; mi < 4; ++mi) {
#pragma unroll
    for (int ni = 0; ni < 4; ++ni) {
      const int n = n0 + wc * 64 + ni * 16 + c;
      const int h = n >> 6, hd = n & 63;
      if (z < 2) {
#pragma unroll
        for (int r = 0; r < 4; ++r) {
          const int m = m0 + wr * 64 + mi * 16 + g * 4 + r;
          const int b = m >> 11, s = m & 2047;
          dst[((size_t)(b * H_ + h) * S_ + s) * HD_ + hd] = f2bf(acc[mi][ni][r] * osc);
        }
      } else {
        const int m = m0 + wr * 64 + mi * 16 + g * 4;
        const int b = m >> 11, s = m & 2047;
        ushort4v pk;
#pragma unroll
        for (int r = 0; r < 4; ++r) pk[r] = f2bf(acc[mi][ni][r]);
        *(ushort4v*)&dst[((size_t)(b * H_ + h) * HD_ + hd) * S_ + s] = pk;
      }
    }
  }
}

// ---------------------------------------------------------------------------
// Kernel B: attention with 32x32x16 MFMA. 4 waves x 32 q-rows = 128 q/block,
// grid 512 (32 bh x 16 q-blocks), XCD-chunked bh swizzle (4 heads/XCD).
// Per-q cost vs 16x16 version: staging x0.5, barriers x0.5, LDS reads ~x0.6,
// MFMA cycles x0.8. Swapped QK^T (mfma32(K,Q)): D col=lane&31=q,
// row=(reg&3)+8*(reg>>2)+4*(lane>>5)=k. A/B frags: row=lane&31,
// k/d=(lane>>5)*8+j. Softmax: no-max (scores bounded, shift-invariant =>
// exact), scale pre-folded into Q, 1-shuffle expsum reduce. Stores: P bf16
// through per-wave Ps tile, re-read row-major -> 256B-contiguous f32x4 nt
// stores. Barriers lgkm-only (stores drain in background).
// ---------------------------------------------------------------------------
__global__ __launch_bounds__(256) void attn_kernel(
    const unsigned short* __restrict__ qh, const unsigned short* __restrict__ kh,
    const unsigned short* __restrict__ vt, float* __restrict__ attn,
    unsigned short* __restrict__ comb)
{
  __shared__ unsigned short Ks[64][72];       // K tile [k][d], pad 64->72
  __shared__ unsigned short Vs[64][72];       // V^T tile [hd][k], pad
  __shared__ unsigned short Ps[4][32][72];    // per-wave P tile [q][k], pad

  const int tid = threadIdx.x;
  const int lane = tid & 63, w = tid >> 6;
  const int q32 = lane & 31, hi = lane >> 5;  // 32x32 frag coords
  const int c = lane & 15, g = lane >> 4;     // staging/store coords

  // bijective chunked XCD swizzle: XCD r gets bh in [4r, 4r+4)
  const int lin = blockIdx.x;
  const int swz = (lin & 7) * 64 + (lin >> 3);
  const int bh = swz >> 4;
  const int q0 = (swz & 15) * 128;
  const int qw = q0 + w * 32;                 // wave's q base

  const unsigned short* Qb = qh + (size_t)bh * S_ * HD_;
  const unsigned short* Kb = kh + (size_t)bh * S_ * HD_;
  const unsigned short* Vb = vt + (size_t)bh * HD_ * S_;
  float* attnb = attn + (size_t)bh * S_ * S_;

  const int sr = tid >> 2;            // staging row 0..63
  const int scol = (tid & 3) * 16;    // 0,16,32,48

  // Q fragments (B-operand): n=q32, d = t*16 + hi*8 + j
  bf16x8 aQ[4];
#pragma unroll
  for (int t = 0; t < 4; ++t)
    aQ[t] = *(const bf16x8*)(Qb + (size_t)(qw + q32) * HD_ + t * 16 + hi * 8);

  const unsigned short* Kst = Kb + (size_t)sr * HD_ + scol;
  const unsigned short* Vst = Vb + (size_t)sr * S_ + scol;

  // ---- pass 1: row expsums ----
  float l4[4] = {0.f, 0.f, 0.f, 0.f};
  ushort8 kr0 = *(const ushort8*)Kst;
  ushort8 kr1 = *(const ushort8*)(Kst + 8);

  for (int kt = 0; kt < 32; ++kt) {
    *(ushort8*)&Ks[sr][scol]     = kr0;
    *(ushort8*)&Ks[sr][scol + 8] = kr1;
    LGKM_BARRIER();
    if (kt < 31) {
      const unsigned short* p = Kst + (size_t)(kt + 1) * 64 * HD_;
      kr0 = *(const ushort8*)p;
      kr1 = *(const ushort8*)(p + 8);
    }
#pragma unroll
    for (int kb = 0; kb < 2; ++kb) {
      f32x16 p = (f32x16)(0.f);
#pragma unroll
      for (int t = 0; t < 4; ++t)
        p = mfma32(*(bf16x8*)&Ks[kb * 32 + q32][t * 16 + hi * 8], aQ[t], p);
#pragma unroll
      for (int r = 0; r < 16; ++r) l4[r & 3] += fexp2(p[r]);
    }
    LGKM_BARRIER();
  }
  float l = (l4[0] + l4[1]) + (l4[2] + l4[3]);
  l += __shfl_xor(l, 32);
  const float invl = 1.f / l;

  // ---- pass 2: QK -> normalized P (bf16, Ps) -> PV; coalesced attn stores ----
  f32x16 ctx0 = (f32x16)(0.f), ctx1 = (f32x16)(0.f);

  // store-phase roles: lane (c,g) stores row qw + it*4 + g, cols c*4..c*4+3
  float* srow = attnb + (size_t)(qw + g) * S_ + c * 4;

  kr0 = *(const ushort8*)Kst;
  kr1 = *(const ushort8*)(Kst + 8);
  ushort8 vr0 = *(const ushort8*)Vst;
  ushort8 vr1 = *(const ushort8*)(Vst + 8);

  for (int kt = 0; kt < 32; ++kt) {
    *(ushort8*)&Ks[sr][scol]     = kr0;
    *(ushort8*)&Ks[sr][scol + 8] = kr1;
    *(ushort8*)&Vs[sr][scol]     = vr0;
    *(ushort8*)&Vs[sr][scol + 8] = vr1;
    LGKM_BARRIER();
    if (kt < 31) {                       // prefetch BEFORE this tile's stores
      const unsigned short* p = Kst + (size_t)(kt + 1) * 64 * HD_;
      const unsigned short* q = Vst + (kt + 1) * 64;
      kr0 = *(const ushort8*)p;
      kr1 = *(const ushort8*)(p + 8);
      vr0 = *(const ushort8*)q;
      vr1 = *(const ushort8*)(q + 8);
    }

    // QK^T + normalize + P->Ps (per lane: one q row, 16 k values per kb)
#pragma unroll
    for (int kb = 0; kb < 2; ++kb) {
      f32x16 p = (f32x16)(0.f);
#pragma unroll
      for (int t = 0; t < 4; ++t)
        p = mfma32(*(bf16x8*)&Ks[kb * 32 + q32][t * 16 + hi * 8], aQ[t], p);
#pragma unroll
      for (int j = 0; j < 4; ++j) {       // regs 4j..4j+3 -> k = kb*32+8j+4hi+r
        ushort4v pk;
#pragma unroll
        for (int r = 0; r < 4; ++r) pk[r] = f2bf(fexp2(p[4 * j + r]) * invl);
        *(ushort4v*)&Ps[w][q32][kb * 32 + 8 * j + 4 * hi] = pk;
      }
    }

    // PV: A = Ps rows (q=lane&31), B = Vs rows (hd = hb*32 + lane&31)
    bf16x8 pa[4];
#pragma unroll
    for (int t = 0; t < 4; ++t)
      pa[t] = *(bf16x8*)&Ps[w][q32][t * 16 + hi * 8];
#pragma unroll
    for (int t = 0; t < 4; ++t) {
      ctx0 = mfma32(pa[t], *(bf16x8*)&Vs[q32][t * 16 + hi * 8],      ctx0);
      ctx1 = mfma32(pa[t], *(bf16x8*)&Vs[32 + q32][t * 16 + hi * 8], ctx1);
    }

    // coalesced attn store: re-read Ps row-major; 16 lanes x 16B = 256B/row
#pragma unroll
    for (int it = 0; it < 8; ++it) {
      ushort4v pb = *(ushort4v*)&Ps[w][it * 4 + g][c * 4];
      f32x4 pf;
#pragma unroll
      for (int r = 0; r < 4; ++r) pf[r] = bf2f(pb[r]);
      __builtin_nontemporal_store(pf, (f32x4*)(srow + (size_t)it * 4 * S_ + kt * 64));
    }
    LGKM_BARRIER();
  }

  // epilogue: combined[b][s][h*64+hd] (bf16); ctx D: col=hd(lane&31), row=q
  const int b = bh >> 4, h = bh & 15;
#pragma unroll
  for (int r = 0; r < 16; ++r) {
    const int qrow = (r & 3) + 8 * (r >> 2) + 4 * hi;
    unsigned short* cb = comb + (size_t)(b * S_ + qw + qrow) * D_ + h * 64 + q32;
    cb[0]  = f2bf(ctx0[r]);
    cb[32] = f2bf(ctx1[r]);
  }
}

// ---------------------------------------------------------------------------
// Kernel C: output projection. out[m][n] = sum_k comb[m][k] * wo[n][k], f32 out.
// ---------------------------------------------------------------------------
__global__ __launch_bounds__(256) void out_proj_kernel(
    const unsigned short* __restrict__ comb, const float* __restrict__ wo,
    float* __restrict__ out)
{
  __shared__ unsigned short As[128][40];
  __shared__ unsigned short Bs[128][40];

  const int lin = blockIdx.x + 8 * blockIdx.y;
  const int swz = (lin & 7) * 32 + (lin >> 3);
  const int bx = swz & 7, by = swz >> 3;

  const int tid = threadIdx.x;
  const int lane = tid & 63, wid = tid >> 6;
  const int c = lane & 15, g = lane >> 4;
  const int wr = wid >> 1, wc = wid & 1;
  const int m0 = by * 128, n0 = bx * 128;
  const int sr = tid >> 1, sh = tid & 1;

  const unsigned short* Apb = comb + (size_t)(m0 + sr) * D_ + sh * 16;
  const float* Bpb = wo + (size_t)(n0 + sr) * D_ + sh * 16;

  ushort8 ar2[2];
  float br[16];
  f32x4 acc[4][4];
#pragma unroll
  for (int i = 0; i < 4; ++i)
#pragma unroll
    for (int j = 0; j < 4; ++j) acc[i][j] = (f32x4){0.f, 0.f, 0.f, 0.f};

  auto ldg_tile = [&](int kt) {
    ar2[0] = *(const ushort8*)(Apb + kt * 32);
    ar2[1] = *(const ushort8*)(Apb + kt * 32 + 8);
#pragma unroll
    for (int j = 0; j < 4; ++j)
      *(f32x4*)(br + 4 * j) = *(const f32x4*)(Bpb + kt * 32 + 4 * j);
  };
  auto sts_tile = [&]() {
    *(ushort8*)&As[sr][sh * 16]     = ar2[0];
    *(ushort8*)&As[sr][sh * 16 + 8] = ar2[1];
    unsigned short tb[16];
#pragma unroll
    for (int j = 0; j < 16; ++j) tb[j] = f2bf(br[j]);
    *(ushort8*)&Bs[sr][sh * 16]     = *(ushort8*)&tb[0];
    *(ushort8*)&Bs[sr][sh * 16 + 8] = *(ushort8*)&tb[8];
  };

  ldg_tile(0);
  sts_tile();
  __syncthreads();

  for (int kt = 0; kt < 32; ++kt) {
    if (kt < 31) ldg_tile(kt + 1);
    bf16x8 af[4], bfr[4];
#pragma unroll
    for (int i = 0; i < 4; ++i) af[i]  = *(bf16x8*)&As[wr * 64 + i * 16 + c][g * 8];
#pragma unroll
    for (int i = 0; i < 4; ++i) bfr[i] = *(bf16x8*)&Bs[wc * 64 + i * 16 + c][g * 8];
#pragma unroll
    for (int mi = 0; mi < 4; ++mi)
#pragma unroll
      for (int ni = 0; ni < 4; ++ni)
        acc[mi][ni] = mfma16(af[mi], bfr[ni], acc[mi][ni]);
    __syncthreads();
    if (kt < 31) { sts_tile(); __syncthreads(); }
  }

#pragma unroll
  for (int mi = 0; mi < 4; ++mi)
#pragma unroll
    for (int ni = 0; ni < 4; ++ni)
#pragma unroll
      for (int r = 0; r < 4; ++r) {
        const int m = m0 + wr * 64 + mi * 16 + g * 4 + r;
        const int n = n0 + wc * 64 + ni * 16 + c;
        out[(size_t)m * D_ + n] = acc[mi][ni][r];
      }
}

// ---------------------------------------------------------------------------
extern "C" void kernel_launch(void* const* d_in, const int* in_sizes, int n_in,
                              void* d_out, int out_size, void* d_ws, size_t ws_size,
                              hipStream_t stream)
{
  const float* q  = (const float*)d_in[0];
  const float* k  = (const float*)d_in[1];
  const float* v  = (const float*)d_in[2];
  const float* wq = (const float*)d_in[3];
  const float* wk = (const float*)d_in[4];
  const float* wv = (const float*)d_in[5];
  const float* wo = (const float*)d_in[6];

  float* out  = (float*)d_out;
  float* attn = out + (size_t)B_ * S_ * D_;   // tuple order: (out, attn)

  const size_t NE = (size_t)B_ * S_ * D_;
  unsigned short* qh   = (unsigned short*)d_ws;
  unsigned short* kh   = qh + NE;
  unsigned short* vt   = kh + NE;
  unsigned short* comb = vt + NE;

  proj_qkv_kernel<<<dim3(8, 32, 3), dim3(256), 0, stream>>>(q, k, v, wq, wk, wv, qh, kh, vt);
  attn_kernel<<<dim3(512), dim3(256), 0, stream>>>(qh, kh, vt, attn, comb);
  out_proj_kernel<<<dim3(8, 32), dim3(256), 0, stream>>>(comb, wo, out);
}